// Round 9
// baseline (380.568 us; speedup 1.0000x reference)
//
#include <hip/hip_runtime.h>
#include <hip/hip_fp16.h>
#include <math.h>

// Transformer-XL relative multi-head attention, MI355X. B=2,S=2048,D=512,H=8,dh=64.
// Round-21: MEASUREMENT PROBE.  r19 (dense stores) and r20 (dbuf) both null
//   on the ~115us non-attn budget, while a bottom-up model says prep+proj+out
//   should cost ~20-25us total.  4-5x disconnect -> stop theorizing, measure.
//   Probe: idempotent in-kernel repetition (prep x16, proj x8, out x16; reps
//   barrier-separated + memory-clobber to defeat CSE/DCE).  Launch count
//   unchanged.  Any kernel with true cost >= ~5-10us now exceeds attn's 83us
//   per-dispatch and surfaces in rocprof top-5 WITH counters.
//   Decision tree: surfaced kernel = the mass -> diagnose via its counters;
//   nothing surfaces & Dtotal small -> the residual is inter-dispatch
//   overhead -> merge dispatches next round.
//   attn_fused is UNCHANGED (T1 swizzle + T5 setprio, 83us).
//  1. prep        : x,pos fp32->fp16 + 5 weights -> fp16 W^T  [x16 PROBE]
//  2. proj_mfma   : QU/QV PRESCALED, K, Pb, VT                [x8 PROBE]
//  3. attn_fused  : fused pos-GEMM, XCD-swizzled, setprio     [unchanged]
//  4. out_mfma    : out = ctx @ Wo + bo                       [x16 PROBE]

#define S_LEN 2048
#define NH 8
#define DHD 64
#define DM 512
#define NBH 16
#define HEAD_ELEMS (S_LEN * DHD)

// probe repetition counts (idempotent re-execution)
#define REP_PREP 16
#define REP_PROJ 8
#define REP_OUT  16

// workspace byte offsets
#define BY_QU  0u               // fp16 [16][2048][64]  4 MB  (prescaled q+u)
#define BY_QV  4194304u         // fp16 [16][2048][64]  4 MB  (prescaled q+v)
#define BY_K   8388608u         // fp16 [16][2048][64]  4 MB
#define BY_VT  12582912u        // fp16 [16][64][2048]  4 MB
#define BY_PB  16777216u        // fp16 [16][2048][64]  4 MB
#define BY_XH  20971520u        // fp16 [2][2048][512]  4 MB
#define BY_PH  25165824u        // fp16 [2][2048][512]  4 MB
#define BY_WT  29360128u        // fp16 [5][512][512] transposed, 2.62 MB
#define BY_CTX 31981568u        // fp16 [2][2048][512]  4 MB
#define BY_END 36175872u        // end of used workspace
#define WT_MAT_HALFS 262144u

#define GJP 204                 // G row pitch in halfs (408 B)

typedef short v8s __attribute__((ext_vector_type(8)));
typedef float v4f __attribute__((ext_vector_type(4)));

static __device__ __forceinline__ unsigned short f2h(float f) {
    __half h = __float2half(f);
    return *reinterpret_cast<unsigned short*>(&h);
}
static __device__ __forceinline__ float h2f(unsigned short u) {
    __half h = *reinterpret_cast<__half*>(&u);
    return __half2float(h);
}
static __device__ __forceinline__ unsigned pkh(float a, float b) {
    return (unsigned)f2h(a) | ((unsigned)f2h(b) << 16);
}

// read 4 halfs at offset p..p+3 from the 8-half aligned window starting at
// col c0 (c0 % 4 == 0) of LDS row `grow`.  p in 0..3, per-lane constant.
static __device__ __forceinline__ void g_read4(const unsigned short* grow,
                                               int c0, int p,
                                               unsigned short h[4])
{
    uint2 w0 = *(const uint2*)(grow + c0);
    uint2 w1 = *(const uint2*)(grow + c0 + 4);
    unsigned y0 = (p & 2) ? w0.y : w0.x;
    unsigned y1 = (p & 2) ? w1.x : w0.y;
    unsigned y2 = (p & 2) ? w1.y : w1.x;
    unsigned s = (unsigned)(p & 1) * 16u;
    unsigned v01 = __builtin_amdgcn_alignbit(y1, y0, s);
    unsigned v23 = __builtin_amdgcn_alignbit(y2, y1, s);
    h[0] = (unsigned short)(v01 & 0xffff);
    h[1] = (unsigned short)(v01 >> 16);
    h[2] = (unsigned short)(v23 & 0xffff);
    h[3] = (unsigned short)(v23 >> 16);
}

// ---------------------------------------------------------------------------
// prep: conv_inputs + conv_wt fused.  PROBE: body repeated REP_PREP times.
// ---------------------------------------------------------------------------
__global__ __launch_bounds__(256)
void prep(const float* __restrict__ x, const float* __restrict__ pos,
          const float* __restrict__ Wq, const float* __restrict__ Wk,
          const float* __restrict__ Wv, const float* __restrict__ Wp,
          const float* __restrict__ Wo, char* __restrict__ wsb)
{
    __shared__ float T[64][65];
    const int bid = blockIdx.x;
    const int t = threadIdx.x;

    if (bid < 4096) {
        const int zp = bid >> 11;
        const float* src = zp ? pos : x;
        unsigned short* dst = (unsigned short*)(wsb + (zp ? BY_PH : BY_XH));
        int i = ((bid & 2047) * 256 + t) * 4;
        for (int rep = 0; rep < REP_PREP; ++rep) {
            float4 a = *(const float4*)(src + i);
            ushort4 p;
            p.x = f2h(a.x); p.y = f2h(a.y); p.z = f2h(a.z); p.w = f2h(a.w);
            *(ushort4*)(dst + i) = p;
            asm volatile("" ::: "memory");
        }
        return;
    }

    const int f = bid - 4096;          // 0..319
    const int z = f >> 6;              // 0..4
    const int rem = f & 63;
    const int n0 = (rem & 7) * 64, k0 = (rem >> 3) * 64;
    const float* W = (z == 0) ? Wq : (z == 1) ? Wk :
                     (z == 2) ? Wv : (z == 3) ? Wp : Wo;
    unsigned short* WT = (unsigned short*)(wsb + BY_WT) + (size_t)z * WT_MAT_HALFS;
    for (int rep = 0; rep < REP_PREP; ++rep) {
#pragma unroll
        for (int i = 0; i < 4; ++i) {
            int ff = t + i * 256;
            int row = ff >> 4, c4 = ff & 15;
            *(float4*)&T[row][c4 * 4] = *(const float4*)(W + (size_t)(k0 + row) * 512 + n0 + c4 * 4);
        }
        __syncthreads();
#pragma unroll
        for (int i = 0; i < 4; ++i) {
            int ff = t + i * 256;
            int n = ff >> 4, k4 = ff & 15;
            ushort4 p;
            p.x = f2h(T[k4 * 4 + 0][n]); p.y = f2h(T[k4 * 4 + 1][n]);
            p.z = f2h(T[k4 * 4 + 2][n]); p.w = f2h(T[k4 * 4 + 3][n]);
            *(ushort4*)(WT + (size_t)(n0 + n) * 512 + k0 + k4 * 4) = p;
        }
        __syncthreads();
        asm volatile("" ::: "memory");
    }
}

// ---------------------------------------------------------------------------
// proj_mfma: dbuf-staged GEMM (r20).  PROBE: body repeated REP_PROJ times.
// ---------------------------------------------------------------------------
__global__ __launch_bounds__(256)
void proj_mfma(const float* __restrict__ bq, const float* __restrict__ bk,
               const float* __restrict__ bvp,
               const float* __restrict__ uvec, const float* __restrict__ vvec,
               char* __restrict__ wsb)
{
    __shared__ __align__(16) unsigned short SRAW[32768];   // 64 KB (2x A+B)
    unsigned short* T = SRAW;               // epilogue repack [64][132] (alias)

    const int t = threadIdx.x;
    const int wave = t >> 6, lane = t & 63;
    const int quad = lane >> 4, l16 = lane & 15;
    const int wm = wave >> 1, wn = wave & 1;
    const int mode = blockIdx.z;
    const unsigned short* xh = (const unsigned short*)(wsb + BY_XH);
    const unsigned short* ph = (const unsigned short*)(wsb + BY_PH);
    const unsigned short* wt = (const unsigned short*)(wsb + BY_WT);

    const unsigned short* matA;
    const unsigned short* matB;
    if (mode != 2) {
        const int mat = (mode == 0) ? 0 : (mode == 1) ? 1 : 3;
        matA = wt + (size_t)mat * WT_MAT_HALFS + (size_t)(blockIdx.y * 128) * 512;
        matB = ((mode == 3) ? ph : xh) + (size_t)(blockIdx.x * 128) * 512;
    } else {
        matA = xh + (size_t)(blockIdx.x * 128) * 512;
        matB = wt + (size_t)2 * WT_MAT_HALFS + (size_t)(blockIdx.y * 128) * 512;
    }

    const int rowl = lane >> 3, chl = lane & 7;   // 8 rows / 8 chunks per inst

#define PSTAGE(KB, AB, BB)                                                    \
    {                                                                         \
        _Pragma("unroll")                                                     \
        for (int jj = 0; jj < 4; ++jj) {                                      \
            const int j = wave * 4 + jj;                                      \
            const int r = j * 8 + rowl;                                       \
            const int c = chl ^ (r & 7);                                      \
            __builtin_amdgcn_global_load_lds(                                 \
                (const __attribute__((address_space(1))) unsigned int*)       \
                    (matA + (size_t)r * 512 + (KB) * 64 + c * 8),             \
                (__attribute__((address_space(3))) unsigned int*)             \
                    ((AB) + j * 512), 16, 0, 0);                              \
            __builtin_amdgcn_global_load_lds(                                 \
                (const __attribute__((address_space(1))) unsigned int*)       \
                    (matB + (size_t)r * 512 + (KB) * 64 + c * 8),             \
                (__attribute__((address_space(3))) unsigned int*)             \
                    ((BB) + j * 512), 16, 0, 0);                              \
        }                                                                     \
    }

#define PCOMPUTE(AB, BB)                                                      \
    {                                                                         \
        v8s af0[4], af1[4], bf0[4], bf1[4];                                   \
        _Pragma("unroll")                                                     \
        for (int i = 0; i < 4; ++i) {                                         \
            int rA = wm * 64 + i * 16 + l16;                                  \
            const unsigned short* al = (AB) + rA * 64;                        \
            af0[i] = *(const v8s*)(al + ((quad ^ (rA & 7)) * 8));             \
            af1[i] = *(const v8s*)(al + (((4 + quad) ^ (rA & 7)) * 8));       \
            int rB = wn * 64 + i * 16 + l16;                                  \
            const unsigned short* bl = (BB) + rB * 64;                        \
            bf0[i] = *(const v8s*)(bl + ((quad ^ (rB & 7)) * 8));             \
            bf1[i] = *(const v8s*)(bl + (((4 + quad) ^ (rB & 7)) * 8));       \
        }                                                                     \
        _Pragma("unroll")                                                     \
        for (int i = 0; i < 4; ++i)                                           \
            _Pragma("unroll")                                                 \
            for (int j = 0; j < 4; ++j) {                                     \
                acc[i][j] = __builtin_amdgcn_mfma_f32_16x16x32_f16(af0[i], bf0[j], acc[i][j], 0, 0, 0); \
                acc[i][j] = __builtin_amdgcn_mfma_f32_16x16x32_f16(af1[i], bf1[j], acc[i][j], 0, 0, 0); \
            }                                                                 \
    }

    for (int rep = 0; rep < REP_PROJ; ++rep) {

    v4f acc[4][4];
#pragma unroll
    for (int i = 0; i < 4; ++i)
#pragma unroll
        for (int j = 0; j < 4; ++j) acc[i][j] = (v4f){0.f, 0.f, 0.f, 0.f};

    {
        unsigned short* A0 = SRAW;
        unsigned short* B0 = SRAW + 8192;
        unsigned short* A1 = SRAW + 16384;
        unsigned short* B1 = SRAW + 24576;
        PSTAGE(0, A0, B0)
#pragma unroll
        for (int kb = 0; kb < 8; ++kb) {
            __syncthreads();   // drains stage(kb); prior reads of target buf done
            if (kb < 7) {
                if ((kb & 1) == 0) { PSTAGE(kb + 1, A1, B1) }
                else               { PSTAGE(kb + 1, A0, B0) }
            }
            if ((kb & 1) == 0) { PCOMPUTE(A0, B0) }
            else               { PCOMPUTE(A1, B1) }
        }
        __syncthreads();   // staging LDS dead; T alias safe
    }

    const int d0blk = blockIdx.y * 128;
    const int s0blk = blockIdx.x * 128;

    if (mode != 2) {
        const int nsel = (mode == 0) ? 2 : 1;
        for (int sel = 0; sel < nsel; ++sel) {
            unsigned short* dstb =
                (mode == 0) ? (unsigned short*)(wsb + (sel ? BY_QV : BY_QU))
                            : (unsigned short*)(wsb + (mode == 1 ? BY_K : BY_PB));
            for (int hs = 0; hs < 2; ++hs) {
                if (wn == hs) {
#pragma unroll
                    for (int i = 0; i < 4; ++i) {
                        int d_loc = wm * 64 + i * 16 + quad * 4;
                        int db = d0blk + d_loc;
                        float4 addv = make_float4(0.f, 0.f, 0.f, 0.f);
                        float sc = 1.f;
                        if (mode == 0) {
                            float4 b4 = *(const float4*)(bq + db);
                            const float* uv = sel ? vvec : uvec;
                            float4 u4 = *(const float4*)(uv + db);
                            addv = make_float4(b4.x + u4.x, b4.y + u4.y,
                                               b4.z + u4.z, b4.w + u4.w);
                            sc = 0.04419417382415922f;
                        } else if (mode == 1) {
                            addv = *(const float4*)(bk + db);
                        }
#pragma unroll
                        for (int j = 0; j < 4; ++j) {
                            int s_loc = j * 16 + l16;
                            ushort4 pk;
                            pk.x = f2h((acc[i][j][0] + addv.x) * sc);
                            pk.y = f2h((acc[i][j][1] + addv.y) * sc);
                            pk.z = f2h((acc[i][j][2] + addv.z) * sc);
                            pk.w = f2h((acc[i][j][3] + addv.w) * sc);
                            *(ushort4*)&T[s_loc * 132 + d_loc] = pk;
                        }
                    }
                }
                __syncthreads();
                {
                    const int col4 = t & 31, rowb = t >> 5;
#pragma unroll
                    for (int ii = 0; ii < 8; ++ii) {
                        int row = rowb + ii * 8;
                        int s = s0blk + hs * 64 + row;
                        int bb = s >> 11, srow = s & 2047;
                        int d = d0blk + col4 * 4;
                        int h = d >> 6, dl = d & 63;
                        *(ushort4*)(dstb + ((size_t)(bb * NH + h) * S_LEN + srow) * DHD + dl) =
                            *(const ushort4*)&T[row * 132 + col4 * 4];
                    }
                }
                __syncthreads();
            }
        }
    } else {
        unsigned short* vt = (unsigned short*)(wsb + BY_VT);
        for (int hs = 0; hs < 2; ++hs) {
            if (wn == hs) {
#pragma unroll
                for (int j = 0; j < 4; ++j) {
                    int d_loc = j * 16 + l16;
                    int d = d0blk + hs * 64 + d_loc;
                    float bval = bvp[d];
#pragma unroll
                    for (int i = 0; i < 4; ++i) {
                        int s_loc = wm * 64 + i * 16 + quad * 4;
                        ushort4 pk;
                        pk.x = f2h(acc[i][j][0] + bval);
                        pk.y = f2h(acc[i][j][1] + bval);
                        pk.z = f2h(acc[i][j][2] + bval);
                        pk.w = f2h(acc[i][j][3] + bval);
                        *(ushort4*)&T[d_loc * 132 + s_loc] = pk;
                    }
                }
            }
            __syncthreads();
            {
                const int col4 = t & 31, rowb = t >> 5;
#pragma unroll
                for (int ii = 0; ii < 8; ++ii) {
                    int row = rowb + ii * 8;            // d within half
                    int d = d0blk + hs * 64 + row;
                    int h = d >> 6, dl = d & 63;
                    int s = s0blk + col4 * 4;
                    int bb = s >> 11, srow = s & 2047;
                    *(ushort4*)(vt + ((size_t)(bb * NH + h) * DHD + dl) * S_LEN + srow) =
                        *(const ushort4*)&T[row * 132 + col4 * 4];
                }
            }
            __syncthreads();
        }
    }

    asm volatile("" ::: "memory");
    }   // rep
#undef PSTAGE
#undef PCOMPUTE
}

// ---------------------------------------------------------------------------
// Flash attention: UNCHANGED from r19/r20 (T1 XCD swizzle + T5 setprio).
// ---------------------------------------------------------------------------
__global__ __launch_bounds__(256, 2)
void attn_fused(const unsigned short* __restrict__ qu,
                const unsigned short* __restrict__ kdat,
                const unsigned short* __restrict__ vtg,
                const unsigned short* __restrict__ qvg,
                const unsigned short* __restrict__ pbg,
                unsigned short* __restrict__ ctx)
{
    __shared__ __align__(16) unsigned short Kbuf[8192];     // 16 KB
    __shared__ __align__(16) unsigned short Vbuf[8192];     // 16 KB
    __shared__ __align__(16) unsigned short Gb[80 * GJP];   // 31.9 KB

    const int t = threadIdx.x;
    const int wave = t >> 6, lane = t & 63;
    const int quad = lane >> 4, l16 = lane & 15;
    const int vb = ((blockIdx.x & 7) << 6) | (blockIdx.x >> 3);   // T1 swizzle
    const int g = vb >> 5, qt = vb & 31;
    const int qb = qt * 64;
    const int q0w = qb + wave * 16;
    const int ql = wave * 16 + l16;          // q-local in [0,64)
    const int q = qb + ql;
    const int t_mix = qb >> 7;               // diagonal k-tile index
    const int dq = 63 - ql;
    const int pA = dq & 3;
    const int ca_add = (dq - pA) + 4;        // A-read aligned col bias

    const unsigned short* QU = qu   + (size_t)g * HEAD_ELEMS;
    const unsigned short* Kg = kdat + (size_t)g * HEAD_ELEMS;
    const unsigned short* Vg = vtg  + (size_t)g * HEAD_ELEMS;
    const unsigned short* QV = qvg  + (size_t)g * HEAD_ELEMS;
    const unsigned short* Pb = pbg  + (size_t)g * HEAD_ELEMS;

    // staging lane roles (constant per thread)
    const int krow_l = lane >> 3, kch_l = lane & 7;    // within 8-row K group
    const int vrow_l = lane >> 4, vch_l = lane & 15;   // within 4-row V group

#define STAGE_KV(TT)                                                          \
    {                                                                         \
        const int k0s = (TT) * 128;                                           \
        _Pragma("unroll")                                                     \
        for (int jj = 0; jj < 4; ++jj) {                                      \
            const int j = wave * 4 + jj;                                      \
            {                                                                 \
                int kr = j * 8 + krow_l;                                      \
                int kc = kch_l ^ (kr & 7);                                    \
                __builtin_amdgcn_global_load_lds(                             \
                    (const __attribute__((address_space(1))) unsigned int*)   \
                        (Kg + (size_t)(k0s + kr) * DHD + kc * 8),             \
                    (__attribute__((address_space(3))) unsigned int*)         \
                        (Kbuf + j * 512), 16, 0, 0);                          \
            }                                                                 \
            {                                                                 \
                int vr = j * 4 + vrow_l;                                      \
                int vc = vch_l ^ (vr & 15);                                   \
                __builtin_amdgcn_global_load_lds(                             \
                    (const __attribute__((address_space(1))) unsigned int*)   \
                        (Vg + (size_t)vr * S_LEN + k0s + vc * 8),             \
                    (__attribute__((address_space(3))) unsigned int*)         \
                        (Vbuf + j * 512), 16, 0, 0);                          \
            }                                                                 \
        }                                                                     \
    }

#define G_LOAD_AF(JB0)                                                        \
    {                                                                         \
        _Pragma("unroll")                                                     \
        for (int jt2 = 0; jt2 < 3; ++jt2) {                                   \
            int j = (JB0) + (wave * 3 + jt2) * 16 + l16;                      \
            j = j < 0 ? 0 : (j > 2047 ? 2047 : j);                            \
            af0[jt2] = *(const v8s*)(Pb + (size_t)j * DHD + quad * 8);        \
            af1[jt2] = *(const v8s*)(Pb + (size_t)j * DHD + 32 + quad * 8);   \
        }                                                                     \
    }

#define G_MFMA_STORE(NQT)                                                     \
    {                                                                         \
        __builtin_amdgcn_s_setprio(1);                                        \
        _Pragma("unroll")                                                     \
        for (int jt2 = 0; jt2 < 3; ++jt2) {                                   \
            const int colb = 4 + (wave * 3 + jt2) * 16 + quad * 4;            \
            _Pragma("unroll")                                                 \
            for (int qt2 = 0; qt2 < (NQT); ++qt2) {                           \
                v4f c = (v4f){0.f, 0.f, 0.f, 0.f};                            \
                c = __builtin_amdgcn_mfma_f32_16x16x32_f16(af0[jt2], qvf0[qt2], c, 0, 0, 0); \
                c = __builtin_amdgcn_mfma_f32_16x16x32_f16(af1[jt2], qvf1[qt2], c, 0, 0, 0); \
                unsigned short* gr = Gb + (qt2 * 16 + l16) * GJP + colb;      \
                *(unsigned*)gr       = pkh(c[0], c[1]);                       \
                *(unsigned*)(gr + 2) = pkh(c[2], c[3]);                       \
            }                                                                 \
        }                                                                     \
        __builtin_amdgcn_s_setprio(0);                                        \
    }

// MODE: 0 = unconditional, 1 = only k<=q (diagonal pass A)
#define EXTRACT_A(MODE)                                                       \
    {                                                                         \
        const unsigned short* grA = Gb + ql * GJP;                            \
        _Pragma("unroll")                                                     \
        for (int nt = 0; nt < 8; ++nt) {                                      \
            unsigned short hA[4];                                             \
            g_read4(grA, nt * 16 + quad * 4 + ca_add, pA, hA);                \
            _Pragma("unroll")                                                 \
            for (int reg = 0; reg < 4; ++reg) {                               \
                float pv = h2f(hA[reg]);                                      \
                if (MODE) {                                                   \
                    int k = k0 + nt * 16 + quad * 4 + reg;                    \
                    pv = (k <= q) ? pv : 0.f;                                 \
                }                                                             \
                sacc[nt][reg] += pv;                                          \
            }                                                                 \
        }                                                                     \
    }

// MODE: 0 = unconditional, 1 = zero at k==q+1, 2 = only k>=q+2 (diag pass B)
#define EXTRACT_B(MODE)                                                       \
    {                                                                         \
        const unsigned short* grB = Gb + (ql + 1) * GJP;                      \
        const int Ec = k0 - qb - ql - 2 - jb0B + 4;                           \
        const int pB = Ec & 3;                                                \
        _Pragma("unroll")                                                     \
        for (int nt = 0; nt < 8; ++nt) {                                      \
            int eB = nt * 16 + quad * 4 + Ec;                                 \
            int cB0 = eB - pB; if (cB0 < 0) cB0 = 0;                          \
            unsigned short hB[4];                                             \
            g_read4(grB, cB0, pB, hB);                                        \
            _Pragma("unroll")                                                 \
            for (int reg = 0; reg < 4; ++reg) {                               \
                float pv = h2f(hB[reg]);                                      \
                int k = k0 + nt * 16 + quad * 4 + reg;                        \
                if ((MODE) == 1) pv = (k == q + 1) ? 0.f : pv;                \
                if ((MODE) == 2) pv = (k >= q + 2) ? pv : 0.f;                \
                sacc[nt][reg] += pv;                                          \
            }                                                                 \
        }                                                                     \
    }

    // prologue: stage tile 0; load resident fragments
    STAGE_KV(0)

    // qv fragments (G B-operand): 5 q-tiles (rows qb..qb+79, clamped)
    v8s qvf0[5], qvf1[5];
#pragma unroll
    for (int qt2 = 0; qt2 < 5; ++qt2) {
        int r = qb + qt2 * 16 + l16;
        if (r > 2047) r = 2047;
        qvf0[qt2] = *(const v8s*)(QV + (size_t)r * DHD + quad * 8);
        qvf1[qt2] = *(const v8s*)(QV + (size_t)r * DHD + 32 + quad * 8);
    }
    const v8s bq0 = *(const v8s*)(QU + (size_t)q * DHD + quad * 8);
    const v8s bq1 = *(const v8s*)(QU + (size_t)q * DHD + 32 + quad * 8);

    float m_run = -1e30f, l_run = 0.f;
    v4f accv[4];
#pragma unroll
    for (int r = 0; r < 4; ++r) accv[r] = (v4f){0.f, 0.f, 0.f, 0.f};

    for (int tt = 0; tt < 16; ++tt) {
        const int k0 = tt * 128;
        int jb0B = k0 - qb - 65; if (jb0B < 0) jb0B = 0;
        const int jb0_1 = (tt <= t_mix) ? (1984 + k0 - qb) : jb0B;

        // issue pb-window loads early (fly under QK)
        v8s af0[3], af1[3];
        G_LOAD_AF(jb0_1)

        __syncthreads();   // stage(tt) complete & visible

        // QK^T from Kbuf (swizzled ds_read_b128); QU prescaled
        v4f sacc[8];
        __builtin_amdgcn_s_setprio(1);
#pragma unroll
        for (int nt = 0; nt < 8; ++nt) {
            int r = nt * 16 + l16;
            const unsigned short* kl = Kbuf + r * 64;
            v8s a0 = *(const v8s*)(kl + ((quad ^ (r & 7)) * 8));
            v8s a1 = *(const v8s*)(kl + (((4 + quad) ^ (r & 7)) * 8));
            v4f c = (v4f){0.f, 0.f, 0.f, 0.f};
            c = __builtin_amdgcn_mfma_f32_16x16x32_f16(a0, bq0, c, 0, 0, 0);
            c = __builtin_amdgcn_mfma_f32_16x16x32_f16(a1, bq1, c, 0, 0, 0);
            sacc[nt] = c;
        }
        __builtin_amdgcn_s_setprio(0);

        // G window 1 build + extraction (per tile class; block-uniform)
        if (tt < t_mix) {
            G_MFMA_STORE(4)
            __syncthreads();
            EXTRACT_A(0)
        } else if (tt == t_mix) {
            G_MFMA_STORE(4)
            __syncthreads();
            EXTRACT_A(1)
            __syncthreads();          // A reads done before B overwrites G
            G_LOAD_AF(jb0B)
            G_MFMA_STORE(5)
            __syncthreads();
            EXTRACT_B(2)
        } else {
            G_MFMA_STORE(5)
            __syncthreads();
            if (tt == t_mix + 1) {
                EXTRACT_B(1)
            } else {
                EXTRACT_B(0)
            }
        }

        // online softmax (inputs already scaled)
        float tm = -1e30f;
#pragma unroll
        for (int nt = 0; nt < 8; ++nt)
#pragma unroll
            for (int reg = 0; reg < 4; ++reg) tm = fmaxf(tm, sacc[nt][reg]);
        tm = fmaxf(tm, __shfl_xor(tm, 16));
        tm = fmaxf(tm, __shfl_xor(tm, 32));
        float mn = fmaxf(m_run, tm);
        float al = __expf(m_run - mn);
        float rs = 0.f;
#pragma unroll
        for (int nt = 0; nt < 8; ++nt)
#pragma unroll
            for (int reg = 0; reg < 4; ++reg) {
                sacc[nt][reg] = __expf(sacc[nt][reg] - mn);
                rs += sacc[nt][reg];
            }
        rs += __shfl_xor(rs, 16);
        rs += __shfl_xor(rs, 32);
        l_run = l_run * al + rs;
        m_run = mn;

        float alr[4];
#pragma unroll
        for (int reg = 0; reg < 4; ++reg) alr[reg] = __shfl(al, quad * 4 + reg);
#pragma unroll
        for (int ntd = 0; ntd < 4; ++ntd)
#pragma unroll
            for (int reg = 0; reg < 4; ++reg) accv[ntd][reg] *= alr[reg];

        // pack P to fp16 word-pairs
        unsigned pk[8][2];
#pragma unroll
        for (int nt = 0; nt < 8; ++nt) {
            pk[nt][0] = pkh(sacc[nt][0], sacc[nt][1]);
            pk[nt][1] = pkh(sacc[nt][2], sacc[nt][3]);
        }

        // PV: A-fragment via shfl transpose, B from Vbuf (swizzled)
        const int sA = l16 + ((quad & 1) * 32);
        const bool hi = (quad >= 2);
#pragma unroll
        for (int c4 = 0; c4 < 4; ++c4) {
            unsigned a0A = __shfl((int)pk[c4 * 2][0], sA);
            unsigned a1A = __shfl((int)pk[c4 * 2][1], sA);
            unsigned a0B = __shfl((int)pk[c4 * 2][0], sA + 16);
            unsigned a1B = __shfl((int)pk[c4 * 2][1], sA + 16);
            unsigned b0A = __shfl((int)pk[c4 * 2 + 1][0], sA);
            unsigned b1A = __shfl((int)pk[c4 * 2 + 1][1], sA);
            unsigned b0B = __shfl((int)pk[c4 * 2 + 1][0], sA + 16);
            unsigned b1B = __shfl((int)pk[c4 * 2 + 1][1], sA + 16);
            union { unsigned u[4]; v8s v; } apu;
            apu.u[0] = hi ? b0A : a0A;
            apu.u[1] = hi ? b1A : a1A;
            apu.u[2] = hi ? b0B : a0B;
            apu.u[3] = hi ? b1B : a1B;
            __builtin_amdgcn_s_setprio(1);
#pragma unroll
            for (int ntd = 0; ntd < 4; ++ntd) {
                int d = ntd * 16 + l16;
                v8s bv8 = *(const v8s*)(Vbuf + d * 128 +
                                        (((c4 * 4 + quad) ^ (d & 15)) * 8));
                accv[ntd] = __builtin_amdgcn_mfma_f32_16x16x32_f16(apu.v, bv8, accv[ntd], 0, 0, 0);
            }
            __builtin_amdgcn_s_setprio(0);
        }

        __syncthreads();   // all waves done with Kbuf/Vbuf/Gb
        if (tt < 15) STAGE_KV(tt + 1)
    }
#undef STAGE_KV
#undef G_LOAD_AF
#undef G_MFMA_STORE
#undef EXTRACT_A
#undef EXTRACT_B

    // epilogue: each wave owns its 16 q-rows completely.
    const int bb = g >> 3, h = g & 7;
    float inv[4];
#pragma unroll
    for (int reg = 0; reg < 4; ++reg)
        inv[reg] = 1.f / __shfl(l_run, quad * 4 + reg);
#pragma unroll
    for (int ntd = 0; ntd < 4; ++ntd)
#pragma unroll
        for (int reg = 0; reg < 4; ++reg) {
            int qq = q0w + quad * 4 + reg;
            ctx[((size_t)(bb * S_LEN + qq)) * DM + h * DHD + ntd * 16 + l16] =
                f2h(accv[ntd][reg] * inv[reg]);
        }
}

// ---------------------------------------------------------------------------
// out_mfma: dbuf-staged + dense epilogue (r20).  PROBE: repeated REP_OUT.
// ---------------------------------------------------------------------------
__global__ __launch_bounds__(256)
void out_mfma(const float* __restrict__ bo, const char* __restrict__ wsb,
              float* __restrict__ out)
{
    __shared__ __align__(16) unsigned char ORAW[65536];    // 64 KB (2x A+B)
    float* TO = (float*)ORAW;                              // epilogue [64][132]

    const int t = threadIdx.x;
    const int wave = t >> 6, lane = t & 63;
    const int quad = lane >> 4, l16 = lane & 15;
    const int wm = wave >> 1, wn = wave & 1;
    const unsigned short* matA = (const unsigned short*)(wsb + BY_WT)
                                 + (size_t)4 * WT_MAT_HALFS
                                 + (size_t)(blockIdx.y * 128) * 512;
    const unsigned short* matB = (const unsigned short*)(wsb + BY_CTX)
                                 + (size_t)(blockIdx.x * 128) * 512;

    const int rowl = lane >> 3, chl = lane & 7;

#define OSTAGE(KB, AB, BB)                                                    \
    {                                                                         \
        _Pragma("unroll")                                                     \
        for (int jj = 0; jj < 4; ++jj) {                                      \
            const int j = wave * 4 + jj;                                      \
            const int r = j * 8 + rowl;                                       \
            const int c = chl ^ (r & 7);                                      \
            __builtin_amdgcn_global_load_lds(                                 \
                (const __attribute__((address_space(1))) unsigned int*)       \
                    (matA + (size_t)r * 512 + (KB) * 64 + c * 8),             \
                (__attribute__((address_space(3))) unsigned int*)             \
                    ((AB) + j * 512), 16, 0, 0);                              \
            __builtin_amdgcn_global_load_lds(                                 \
                (const __attribute__((address_space(1))) unsigned int*)       \
                    (matB + (size_t)r * 512 + (KB) * 64 + c * 8),             \
                (__attribute__((address_space(3))) unsigned int*)             \
                    ((BB) + j * 512), 16, 0, 0);                              \
        }                                                                     \
    }

#define OCOMPUTE(AB, BB)                                                      \
    {                                                                         \
        v8s af0[4], af1[4], bf0[4], bf1[4];                                   \
        _Pragma("unroll")                                                     \
        for (int i = 0; i < 4; ++i) {                                         \
            int rA = wm * 64 + i * 16 + l16;                                  \
            const unsigned short* al = (AB) + rA * 64;                        \
            af0[i] = *(const v8s*)(al + ((quad ^ (rA & 7)) * 8));             \
            af1[i] = *(const v8s*)(al + (((4 + quad) ^ (rA & 7)) * 8));       \
            int rB = wn * 64 + i * 16 + l16;                                  \
            const unsigned short* bl = (BB) + rB * 64;                        \
            bf0[i] = *(const v8s*)(bl + ((quad ^ (rB & 7)) * 8));             \
            bf1[i] = *(const v8s*)(bl + (((4 + quad) ^ (rB & 7)) * 8));       \
        }                                                                     \
        _Pragma("unroll")                                                     \
        for (int i = 0; i < 4; ++i)                                           \
            _Pragma("unroll")                                                 \
            for (int j = 0; j < 4; ++j) {                                     \
                acc[i][j] = __builtin_amdgcn_mfma_f32_16x16x32_f16(af0[i], bf0[j], acc[i][j], 0, 0, 0); \
                acc[i][j] = __builtin_amdgcn_mfma_f32_16x16x32_f16(af1[i], bf1[j], acc[i][j], 0, 0, 0); \
            }                                                                 \
    }

    for (int rep = 0; rep < REP_OUT; ++rep) {

    v4f acc[4][4];
#pragma unroll
    for (int i = 0; i < 4; ++i)
#pragma unroll
        for (int j = 0; j < 4; ++j) acc[i][j] = (v4f){0.f, 0.f, 0.f, 0.f};

    {
        unsigned short* A0 = (unsigned short*)ORAW;
        unsigned short* B0 = (unsigned short*)ORAW + 8192;
        unsigned short* A1 = (unsigned short*)ORAW + 16384;
        unsigned short* B1 = (unsigned short*)ORAW + 24576;
        OSTAGE(0, A0, B0)
#pragma unroll
        for (int kb = 0; kb < 8; ++kb) {
            __syncthreads();
            if (kb < 7) {
                if ((kb & 1) == 0) { OSTAGE(kb + 1, A1, B1) }
                else               { OSTAGE(kb + 1, A0, B0) }
            }
            if ((kb & 1) == 0) { OCOMPUTE(A0, B0) }
            else               { OCOMPUTE(A1, B1) }
        }
        __syncthreads();   // staging dead; TO alias safe
    }

    const int n0blk = blockIdx.y * 128;
    const int s0blk = blockIdx.x * 128;

    for (int hs = 0; hs < 2; ++hs) {
        if (wn == hs) {
#pragma unroll
            for (int i = 0; i < 4; ++i) {
                int n_loc = wm * 64 + i * 16 + quad * 4;
#pragma unroll
                for (int j = 0; j < 4; ++j) {
                    int s_loc = j * 16 + l16;
                    *(v4f*)&TO[s_loc * 132 + n_loc] = acc[i][j];
                }
            }
        }
        __syncthreads();
        {
            const int col4 = t & 31, rowb = t >> 5;
            float4 b4 = *(const float4*)(bo + n0blk + col4 * 4);
#pragma unroll
            for (int ii = 0; ii < 8; ++ii) {
                int row = rowb + ii * 8;
                int s = s0blk + hs * 64 + row;
                const float* tr = &TO[row * 132 + col4 * 4];
                float4 v = *(const float4*)tr;
                *(float4*)(out + (size_t)s * DM + n0blk + col4 * 4) =
                    make_float4(v.x + b4.x, v.y + b4.y, v.z + b4.z, v.w + b4.w);
            }
        }
        __syncthreads();
    }

    asm volatile("" ::: "memory");
    }   // rep
#undef OSTAGE
#undef OCOMPUTE
}

// Fallback when ws_size is insufficient: clean mismatch instead of OOB writes.
__global__ void zero_fill(float* __restrict__ p, int n)
{
    int i = blockIdx.x * 256 + threadIdx.x;
    if (i < n) p[i] = 0.f;
}

// ---------------------------------------------------------------------------
extern "C" void kernel_launch(void* const* d_in, const int* in_sizes, int n_in,
                              void* d_out, int out_size, void* d_ws, size_t ws_size,
                              hipStream_t stream)
{
    const float* x   = (const float*)d_in[0];
    const float* pos = (const float*)d_in[1];
    const float* Wq  = (const float*)d_in[2];
    const float* bq  = (const float*)d_in[3];
    const float* Wk  = (const float*)d_in[4];
    const float* bk  = (const float*)d_in[5];
    const float* Wv  = (const float*)d_in[6];
    const float* bv  = (const float*)d_in[7];
    const float* Wp  = (const float*)d_in[8];
    const float* u   = (const float*)d_in[9];
    const float* v   = (const float*)d_in[10];
    const float* Wo  = (const float*)d_in[11];
    const float* bo  = (const float*)d_in[12];
    char* wsb  = (char*)d_ws;
    float* out = (float*)d_out;

    // Workspace guard (no Ppos tensor anymore).
    if (ws_size < (size_t)BY_END + 1024) {
        zero_fill<<<(out_size + 255) / 256, 256, 0, stream>>>(out, out_size);
        return;
    }

    // 1. dtype prep (inputs + weights, single dispatch)  [x16 probe]
    prep<<<dim3(4416), 256, 0, stream>>>(x, pos, Wq, Wk, Wv, Wp, Wo, wsb);

    // 2. projections (fp16 MFMA, dbuf-staged; QU/QV prescaled)  [x8 probe]
    proj_mfma<<<dim3(32, 4, 4), 256, 0, stream>>>(bq, bk, bv, u, v, wsb);

    // 3. fused attention (single dispatch, all 16 batch-heads, XCD-swizzled)
    attn_fused<<<dim3(NBH * 32), 256, 0, stream>>>(
        (const unsigned short*)(wsb + BY_QU),
        (const unsigned short*)(wsb + BY_K),
        (const unsigned short*)(wsb + BY_VT),
        (const unsigned short*)(wsb + BY_QV),
        (const unsigned short*)(wsb + BY_PB),
        (unsigned short*)(wsb + BY_CTX));

    // 4. output projection (fp16 MFMA, dbuf-staged, fp32 out)  [x16 probe]
    out_mfma<<<dim3(32, 4), 256, 0, stream>>>(bo, wsb, out);
}

// Round 10
// 186.861 us; speedup vs baseline: 2.0366x; 2.0366x over previous
//
#include <hip/hip_runtime.h>
#include <hip/hip_fp16.h>
#include <math.h>

// Transformer-XL relative multi-head attention, MI355X. B=2,S=2048,D=512,H=8,dh=64.
// Round-22: proj 8-wave (TLP fix) + attn defer-max (T13) + K-early staging.
//   r21 probe decoded: proj_true = 16.2us (occupancy 10% -> TLP-starved),
//   prep+out = 4.6us, attn = 83us, and ~94us is FIXED harness overhead
//   (consistent across r12-r20; insensitive to dispatch count) -> r19/r20
//   nulls explained: controllable budget is 104us of kernels, not 115us.
//   Fixes: (1) proj_mfma -> 512 threads/block, 8 waves each owning a 64x32
//   subtile (acc 4x2): 16 waves/CU = 4/SIMD, VGPR ~110 (capped via
//   __launch_bounds__(512,4)); staging re-split (2 groups/wave), epilogue
//   re-indexed; identical math order.  (2) attn: T13 defer-max (THR=8,
//   wave-uniform __any; P<=e^8 fits fp16, scale cancels in normalization)
//   + STAGE_KV split: K(t+1) issued after the post-G-store barrier (Kbuf
//   reads complete), V(t+1) after the end barrier -> K flight drains under
//   extract+softmax+PV.
//  1. prep        : x,pos fp32->fp16 + 5 weights -> fp16 W^T (one dispatch).
//  2. proj_mfma   : QU(+u)/QV(+v) PRESCALED, K, Pb [s][d]; VT [d][s].
//  3. attn_fused  : fused pos-GEMM, XCD-swizzled, setprio, defer-max.
//  4. out_mfma    : out(fp32) = ctx @ Wo + bo.

#define S_LEN 2048
#define NH 8
#define DHD 64
#define DM 512
#define NBH 16
#define HEAD_ELEMS (S_LEN * DHD)

// workspace byte offsets
#define BY_QU  0u               // fp16 [16][2048][64]  4 MB  (prescaled q+u)
#define BY_QV  4194304u         // fp16 [16][2048][64]  4 MB  (prescaled q+v)
#define BY_K   8388608u         // fp16 [16][2048][64]  4 MB
#define BY_VT  12582912u        // fp16 [16][64][2048]  4 MB
#define BY_PB  16777216u        // fp16 [16][2048][64]  4 MB
#define BY_XH  20971520u        // fp16 [2][2048][512]  4 MB
#define BY_PH  25165824u        // fp16 [2][2048][512]  4 MB
#define BY_WT  29360128u        // fp16 [5][512][512] transposed, 2.62 MB
#define BY_CTX 31981568u        // fp16 [2][2048][512]  4 MB
#define BY_END 36175872u        // end of used workspace
#define WT_MAT_HALFS 262144u

#define GJP 204                 // G row pitch in halfs (408 B)

typedef short v8s __attribute__((ext_vector_type(8)));
typedef float v4f __attribute__((ext_vector_type(4)));

static __device__ __forceinline__ unsigned short f2h(float f) {
    __half h = __float2half(f);
    return *reinterpret_cast<unsigned short*>(&h);
}
static __device__ __forceinline__ float h2f(unsigned short u) {
    __half h = *reinterpret_cast<__half*>(&u);
    return __half2float(h);
}
static __device__ __forceinline__ unsigned pkh(float a, float b) {
    return (unsigned)f2h(a) | ((unsigned)f2h(b) << 16);
}

// read 4 halfs at offset p..p+3 from the 8-half aligned window starting at
// col c0 (c0 % 4 == 0) of LDS row `grow`.  p in 0..3, per-lane constant.
static __device__ __forceinline__ void g_read4(const unsigned short* grow,
                                               int c0, int p,
                                               unsigned short h[4])
{
    uint2 w0 = *(const uint2*)(grow + c0);
    uint2 w1 = *(const uint2*)(grow + c0 + 4);
    unsigned y0 = (p & 2) ? w0.y : w0.x;
    unsigned y1 = (p & 2) ? w1.x : w0.y;
    unsigned y2 = (p & 2) ? w1.y : w1.x;
    unsigned s = (unsigned)(p & 1) * 16u;
    unsigned v01 = __builtin_amdgcn_alignbit(y1, y0, s);
    unsigned v23 = __builtin_amdgcn_alignbit(y2, y1, s);
    h[0] = (unsigned short)(v01 & 0xffff);
    h[1] = (unsigned short)(v01 >> 16);
    h[2] = (unsigned short)(v23 & 0xffff);
    h[3] = (unsigned short)(v23 >> 16);
}

// ---------------------------------------------------------------------------
// prep: conv_inputs + conv_wt fused into one dispatch (r20, ~2.5us).
// ---------------------------------------------------------------------------
__global__ __launch_bounds__(256)
void prep(const float* __restrict__ x, const float* __restrict__ pos,
          const float* __restrict__ Wq, const float* __restrict__ Wk,
          const float* __restrict__ Wv, const float* __restrict__ Wp,
          const float* __restrict__ Wo, char* __restrict__ wsb)
{
    __shared__ float T[64][65];
    const int bid = blockIdx.x;
    const int t = threadIdx.x;

    if (bid < 4096) {
        const int zp = bid >> 11;
        const float* src = zp ? pos : x;
        unsigned short* dst = (unsigned short*)(wsb + (zp ? BY_PH : BY_XH));
        int i = ((bid & 2047) * 256 + t) * 4;
        float4 a = *(const float4*)(src + i);
        ushort4 p;
        p.x = f2h(a.x); p.y = f2h(a.y); p.z = f2h(a.z); p.w = f2h(a.w);
        *(ushort4*)(dst + i) = p;
        return;
    }

    const int f = bid - 4096;          // 0..319
    const int z = f >> 6;              // 0..4
    const int rem = f & 63;
    const int n0 = (rem & 7) * 64, k0 = (rem >> 3) * 64;
    const float* W = (z == 0) ? Wq : (z == 1) ? Wk :
                     (z == 2) ? Wv : (z == 3) ? Wp : Wo;
    unsigned short* WT = (unsigned short*)(wsb + BY_WT) + (size_t)z * WT_MAT_HALFS;
#pragma unroll
    for (int i = 0; i < 4; ++i) {
        int ff = t + i * 256;
        int row = ff >> 4, c4 = ff & 15;
        *(float4*)&T[row][c4 * 4] = *(const float4*)(W + (size_t)(k0 + row) * 512 + n0 + c4 * 4);
    }
    __syncthreads();
#pragma unroll
    for (int i = 0; i < 4; ++i) {
        int ff = t + i * 256;
        int n = ff >> 4, k4 = ff & 15;
        ushort4 p;
        p.x = f2h(T[k4 * 4 + 0][n]); p.y = f2h(T[k4 * 4 + 1][n]);
        p.z = f2h(T[k4 * 4 + 2][n]); p.w = f2h(T[k4 * 4 + 3][n]);
        *(ushort4*)(WT + (size_t)(n0 + n) * 512 + k0 + k4 * 4) = p;
    }
}

// ---------------------------------------------------------------------------
// proj_mfma, Round-22: 8-wave (512 threads), dbuf-staged, dense epilogue.
// Each wave owns a 64x32 output subtile: wm = wave>>2 (row half), wn = wave&3
// (col quarter); acc[4][2].  Staging: wave issues 2 A-groups + 2 B-groups.
// 2 blocks/CU x 8 waves = 16 waves/CU = 4/SIMD (was 2/SIMD -> r21 measured
// occupancy 10%, TLP-starved at 16.2us).
// ---------------------------------------------------------------------------
__global__ __launch_bounds__(512, 4)
void proj_mfma(const float* __restrict__ bq, const float* __restrict__ bk,
               const float* __restrict__ bvp,
               const float* __restrict__ uvec, const float* __restrict__ vvec,
               char* __restrict__ wsb)
{
    __shared__ __align__(16) unsigned short SRAW[32768];   // 64 KB (2x A+B)
    unsigned short* T = SRAW;               // epilogue repack [64][132] (alias)

    const int t = threadIdx.x;
    const int wave = t >> 6, lane = t & 63;
    const int quad = lane >> 4, l16 = lane & 15;
    const int wm = wave >> 2, wn = wave & 3;      // 2 x 4 of 64x32 subtiles
    const int mode = blockIdx.z;
    const unsigned short* xh = (const unsigned short*)(wsb + BY_XH);
    const unsigned short* ph = (const unsigned short*)(wsb + BY_PH);
    const unsigned short* wt = (const unsigned short*)(wsb + BY_WT);

    const unsigned short* matA;
    const unsigned short* matB;
    if (mode != 2) {
        const int mat = (mode == 0) ? 0 : (mode == 1) ? 1 : 3;
        matA = wt + (size_t)mat * WT_MAT_HALFS + (size_t)(blockIdx.y * 128) * 512;
        matB = ((mode == 3) ? ph : xh) + (size_t)(blockIdx.x * 128) * 512;
    } else {
        matA = xh + (size_t)(blockIdx.x * 128) * 512;
        matB = wt + (size_t)2 * WT_MAT_HALFS + (size_t)(blockIdx.y * 128) * 512;
    }

    const int rowl = lane >> 3, chl = lane & 7;   // 8 rows / 8 chunks per inst

#define PSTAGE(KB, AB, BB)                                                    \
    {                                                                         \
        _Pragma("unroll")                                                     \
        for (int jj = 0; jj < 2; ++jj) {                                      \
            const int j = wave * 2 + jj;                                      \
            const int r = j * 8 + rowl;                                       \
            const int c = chl ^ (r & 7);                                      \
            __builtin_amdgcn_global_load_lds(                                 \
                (const __attribute__((address_space(1))) unsigned int*)       \
                    (matA + (size_t)r * 512 + (KB) * 64 + c * 8),             \
                (__attribute__((address_space(3))) unsigned int*)             \
                    ((AB) + j * 512), 16, 0, 0);                              \
            __builtin_amdgcn_global_load_lds(                                 \
                (const __attribute__((address_space(1))) unsigned int*)       \
                    (matB + (size_t)r * 512 + (KB) * 64 + c * 8),             \
                (__attribute__((address_space(3))) unsigned int*)             \
                    ((BB) + j * 512), 16, 0, 0);                              \
        }                                                                     \
    }

#define PCOMPUTE(AB, BB)                                                      \
    {                                                                         \
        v8s af0[4], af1[4], bf0[2], bf1[2];                                   \
        _Pragma("unroll")                                                     \
        for (int i = 0; i < 4; ++i) {                                         \
            int rA = wm * 64 + i * 16 + l16;                                  \
            const unsigned short* al = (AB) + rA * 64;                        \
            af0[i] = *(const v8s*)(al + ((quad ^ (rA & 7)) * 8));             \
            af1[i] = *(const v8s*)(al + (((4 + quad) ^ (rA & 7)) * 8));       \
        }                                                                     \
        _Pragma("unroll")                                                     \
        for (int jx = 0; jx < 2; ++jx) {                                      \
            int rB = wn * 32 + jx * 16 + l16;                                 \
            const unsigned short* bl = (BB) + rB * 64;                        \
            bf0[jx] = *(const v8s*)(bl + ((quad ^ (rB & 7)) * 8));            \
            bf1[jx] = *(const v8s*)(bl + (((4 + quad) ^ (rB & 7)) * 8));      \
        }                                                                     \
        _Pragma("unroll")                                                     \
        for (int i = 0; i < 4; ++i)                                           \
            _Pragma("unroll")                                                 \
            for (int jx = 0; jx < 2; ++jx) {                                  \
                acc[i][jx] = __builtin_amdgcn_mfma_f32_16x16x32_f16(af0[i], bf0[jx], acc[i][jx], 0, 0, 0); \
                acc[i][jx] = __builtin_amdgcn_mfma_f32_16x16x32_f16(af1[i], bf1[jx], acc[i][jx], 0, 0, 0); \
            }                                                                 \
    }

    v4f acc[4][2];
#pragma unroll
    for (int i = 0; i < 4; ++i)
#pragma unroll
        for (int jx = 0; jx < 2; ++jx) acc[i][jx] = (v4f){0.f, 0.f, 0.f, 0.f};

    {
        unsigned short* A0 = SRAW;
        unsigned short* B0 = SRAW + 8192;
        unsigned short* A1 = SRAW + 16384;
        unsigned short* B1 = SRAW + 24576;
        PSTAGE(0, A0, B0)
#pragma unroll
        for (int kb = 0; kb < 8; ++kb) {
            __syncthreads();   // drains stage(kb); prior reads of target buf done
            if (kb < 7) {
                if ((kb & 1) == 0) { PSTAGE(kb + 1, A1, B1) }
                else               { PSTAGE(kb + 1, A0, B0) }
            }
            if ((kb & 1) == 0) { PCOMPUTE(A0, B0) }
            else               { PCOMPUTE(A1, B1) }
        }
        __syncthreads();   // staging LDS dead; T alias safe
    }
#undef PSTAGE
#undef PCOMPUTE

    const int d0blk = blockIdx.y * 128;
    const int s0blk = blockIdx.x * 128;

    if (mode != 2) {
        // acc[i][jx][reg] = C[d = d0blk + wm*64 + i*16 + quad*4 + reg]
        //                    [s = s0blk + wn*32 + jx*16 + l16]
        const int nsel = (mode == 0) ? 2 : 1;
        for (int sel = 0; sel < nsel; ++sel) {
            unsigned short* dstb =
                (mode == 0) ? (unsigned short*)(wsb + (sel ? BY_QV : BY_QU))
                            : (unsigned short*)(wsb + (mode == 1 ? BY_K : BY_PB));
            for (int hs = 0; hs < 2; ++hs) {
                if ((wn >> 1) == hs) {
#pragma unroll
                    for (int i = 0; i < 4; ++i) {
                        int d_loc = wm * 64 + i * 16 + quad * 4;
                        int db = d0blk + d_loc;
                        float4 addv = make_float4(0.f, 0.f, 0.f, 0.f);
                        float sc = 1.f;
                        if (mode == 0) {
                            float4 b4 = *(const float4*)(bq + db);
                            const float* uv = sel ? vvec : uvec;
                            float4 u4 = *(const float4*)(uv + db);
                            addv = make_float4(b4.x + u4.x, b4.y + u4.y,
                                               b4.z + u4.z, b4.w + u4.w);
                            sc = 0.04419417382415922f;
                        } else if (mode == 1) {
                            addv = *(const float4*)(bk + db);
                        }
#pragma unroll
                        for (int jx = 0; jx < 2; ++jx) {
                            int s_loc = (wn & 1) * 32 + jx * 16 + l16;
                            ushort4 pk;
                            pk.x = f2h((acc[i][jx][0] + addv.x) * sc);
                            pk.y = f2h((acc[i][jx][1] + addv.y) * sc);
                            pk.z = f2h((acc[i][jx][2] + addv.z) * sc);
                            pk.w = f2h((acc[i][jx][3] + addv.w) * sc);
                            *(ushort4*)&T[s_loc * 132 + d_loc] = pk;
                        }
                    }
                }
                __syncthreads();
                {
                    const int col4 = t & 31, rowb = t >> 5;   // 0..15
#pragma unroll
                    for (int ii = 0; ii < 4; ++ii) {
                        int row = rowb + ii * 16;
                        int s = s0blk + hs * 64 + row;
                        int bb = s >> 11, srow = s & 2047;
                        int d = d0blk + col4 * 4;
                        int h = d >> 6, dl = d & 63;
                        *(ushort4*)(dstb + ((size_t)(bb * NH + h) * S_LEN + srow) * DHD + dl) =
                            *(const ushort4*)&T[row * 132 + col4 * 4];
                    }
                }
                __syncthreads();
            }
        }
    } else {
        // acc[i][jx][reg] = V[s = s0blk + wm*64 + i*16 + quad*4 + reg]
        //                    [d = d0blk + wn*32 + jx*16 + l16]
        unsigned short* vt = (unsigned short*)(wsb + BY_VT);
        for (int hs = 0; hs < 2; ++hs) {
            if ((wn >> 1) == hs) {
#pragma unroll
                for (int jx = 0; jx < 2; ++jx) {
                    int d_loc = (wn & 1) * 32 + jx * 16 + l16;
                    int d = d0blk + hs * 64 + d_loc;
                    float bval = bvp[d];
#pragma unroll
                    for (int i = 0; i < 4; ++i) {
                        int s_loc = wm * 64 + i * 16 + quad * 4;
                        ushort4 pk;
                        pk.x = f2h(acc[i][jx][0] + bval);
                        pk.y = f2h(acc[i][jx][1] + bval);
                        pk.z = f2h(acc[i][jx][2] + bval);
                        pk.w = f2h(acc[i][jx][3] + bval);
                        *(ushort4*)&T[d_loc * 132 + s_loc] = pk;
                    }
                }
            }
            __syncthreads();
            {
                const int col4 = t & 31, rowb = t >> 5;   // 0..15
#pragma unroll
                for (int ii = 0; ii < 4; ++ii) {
                    int row = rowb + ii * 16;           // d within half
                    int d = d0blk + hs * 64 + row;
                    int h = d >> 6, dl = d & 63;
                    int s = s0blk + col4 * 4;
                    int bb = s >> 11, srow = s & 2047;
                    *(ushort4*)(vt + ((size_t)(bb * NH + h) * DHD + dl) * S_LEN + srow) =
                        *(const ushort4*)&T[row * 132 + col4 * 4];
                }
            }
            __syncthreads();
        }
    }
}

// ---------------------------------------------------------------------------
// Flash attention, Round-22: r19 core (T1 swizzle + T5 setprio) +
// T13 defer-max + split K/V staging (K issued early, after the post-G-store
// barrier; V after the end barrier).
// ---------------------------------------------------------------------------
__global__ __launch_bounds__(256, 2)
void attn_fused(const unsigned short* __restrict__ qu,
                const unsigned short* __restrict__ kdat,
                const unsigned short* __restrict__ vtg,
                const unsigned short* __restrict__ qvg,
                const unsigned short* __restrict__ pbg,
                unsigned short* __restrict__ ctx)
{
    __shared__ __align__(16) unsigned short Kbuf[8192];     // 16 KB
    __shared__ __align__(16) unsigned short Vbuf[8192];     // 16 KB
    __shared__ __align__(16) unsigned short Gb[80 * GJP];   // 31.9 KB

    const int t = threadIdx.x;
    const int wave = t >> 6, lane = t & 63;
    const int quad = lane >> 4, l16 = lane & 15;
    const int vb = ((blockIdx.x & 7) << 6) | (blockIdx.x >> 3);   // T1 swizzle
    const int g = vb >> 5, qt = vb & 31;
    const int qb = qt * 64;
    const int q0w = qb + wave * 16;
    const int ql = wave * 16 + l16;          // q-local in [0,64)
    const int q = qb + ql;
    const int t_mix = qb >> 7;               // diagonal k-tile index
    const int dq = 63 - ql;
    const int pA = dq & 3;
    const int ca_add = (dq - pA) + 4;        // A-read aligned col bias

    const unsigned short* QU = qu   + (size_t)g * HEAD_ELEMS;
    const unsigned short* Kg = kdat + (size_t)g * HEAD_ELEMS;
    const unsigned short* Vg = vtg  + (size_t)g * HEAD_ELEMS;
    const unsigned short* QV = qvg  + (size_t)g * HEAD_ELEMS;
    const unsigned short* Pb = pbg  + (size_t)g * HEAD_ELEMS;

    // staging lane roles (constant per thread)
    const int krow_l = lane >> 3, kch_l = lane & 7;    // within 8-row K group
    const int vrow_l = lane >> 4, vch_l = lane & 15;   // within 4-row V group

#define STAGE_K(TT)                                                           \
    {                                                                         \
        const int k0s = (TT) * 128;                                           \
        _Pragma("unroll")                                                     \
        for (int jj = 0; jj < 4; ++jj) {                                      \
            const int j = wave * 4 + jj;                                      \
            int kr = j * 8 + krow_l;                                          \
            int kc = kch_l ^ (kr & 7);                                        \
            __builtin_amdgcn_global_load_lds(                                 \
                (const __attribute__((address_space(1))) unsigned int*)       \
                    (Kg + (size_t)(k0s + kr) * DHD + kc * 8),                 \
                (__attribute__((address_space(3))) unsigned int*)             \
                    (Kbuf + j * 512), 16, 0, 0);                              \
        }                                                                     \
    }

#define STAGE_V(TT)                                                           \
    {                                                                         \
        const int k0s = (TT) * 128;                                           \
        _Pragma("unroll")                                                     \
        for (int jj = 0; jj < 4; ++jj) {                                      \
            const int j = wave * 4 + jj;                                      \
            int vr = j * 4 + vrow_l;                                          \
            int vc = vch_l ^ (vr & 15);                                       \
            __builtin_amdgcn_global_load_lds(                                 \
                (const __attribute__((address_space(1))) unsigned int*)       \
                    (Vg + (size_t)vr * S_LEN + k0s + vc * 8),                 \
                (__attribute__((address_space(3))) unsigned int*)             \
                    (Vbuf + j * 512), 16, 0, 0);                              \
        }                                                                     \
    }

#define G_LOAD_AF(JB0)                                                        \
    {                                                                         \
        _Pragma("unroll")                                                     \
        for (int jt2 = 0; jt2 < 3; ++jt2) {                                   \
            int j = (JB0) + (wave * 3 + jt2) * 16 + l16;                      \
            j = j < 0 ? 0 : (j > 2047 ? 2047 : j);                            \
            af0[jt2] = *(const v8s*)(Pb + (size_t)j * DHD + quad * 8);        \
            af1[jt2] = *(const v8s*)(Pb + (size_t)j * DHD + 32 + quad * 8);   \
        }                                                                     \
    }

#define G_MFMA_STORE(NQT)                                                     \
    {                                                                         \
        __builtin_amdgcn_s_setprio(1);                                        \
        _Pragma("unroll")                                                     \
        for (int jt2 = 0; jt2 < 3; ++jt2) {                                   \
            const int colb = 4 + (wave * 3 + jt2) * 16 + quad * 4;            \
            _Pragma("unroll")                                                 \
            for (int qt2 = 0; qt2 < (NQT); ++qt2) {                           \
                v4f c = (v4f){0.f, 0.f, 0.f, 0.f};                            \
                c = __builtin_amdgcn_mfma_f32_16x16x32_f16(af0[jt2], qvf0[qt2], c, 0, 0, 0); \
                c = __builtin_amdgcn_mfma_f32_16x16x32_f16(af1[jt2], qvf1[qt2], c, 0, 0, 0); \
                unsigned short* gr = Gb + (qt2 * 16 + l16) * GJP + colb;      \
                *(unsigned*)gr       = pkh(c[0], c[1]);                       \
                *(unsigned*)(gr + 2) = pkh(c[2], c[3]);                       \
            }                                                                 \
        }                                                                     \
        __builtin_amdgcn_s_setprio(0);                                        \
    }

// MODE: 0 = unconditional, 1 = only k<=q (diagonal pass A)
#define EXTRACT_A(MODE)                                                       \
    {                                                                         \
        const unsigned short* grA = Gb + ql * GJP;                            \
        _Pragma("unroll")                                                     \
        for (int nt = 0; nt < 8; ++nt) {                                      \
            unsigned short hA[4];                                             \
            g_read4(grA, nt * 16 + quad * 4 + ca_add, pA, hA);                \
            _Pragma("unroll")                                                 \
            for (int reg = 0; reg < 4; ++reg) {                               \
                float pv = h2f(hA[reg]);                                      \
                if (MODE) {                                                   \
                    int k = k0 + nt * 16 + quad * 4 + reg;                    \
                    pv = (k <= q) ? pv : 0.f;                                 \
                }                                                             \
                sacc[nt][reg] += pv;                                          \
            }                                                                 \
        }                                                                     \
    }

// MODE: 0 = unconditional, 1 = zero at k==q+1, 2 = only k>=q+2 (diag pass B)
#define EXTRACT_B(MODE)                                                       \
    {                                                                         \
        const unsigned short* grB = Gb + (ql + 1) * GJP;                      \
        const int Ec = k0 - qb - ql - 2 - jb0B + 4;                           \
        const int pB = Ec & 3;                                                \
        _Pragma("unroll")                                                     \
        for (int nt = 0; nt < 8; ++nt) {                                      \
            int eB = nt * 16 + quad * 4 + Ec;                                 \
            int cB0 = eB - pB; if (cB0 < 0) cB0 = 0;                          \
            unsigned short hB[4];                                             \
            g_read4(grB, cB0, pB, hB);                                        \
            _Pragma("unroll")                                                 \
            for (int reg = 0; reg < 4; ++reg) {                               \
                float pv = h2f(hB[reg]);                                      \
                int k = k0 + nt * 16 + quad * 4 + reg;                        \
                if ((MODE) == 1) pv = (k == q + 1) ? 0.f : pv;                \
                if ((MODE) == 2) pv = (k >= q + 2) ? pv : 0.f;                \
                sacc[nt][reg] += pv;                                          \
            }                                                                 \
        }                                                                     \
    }

    // prologue: stage tile 0; load resident fragments
    STAGE_K(0)
    STAGE_V(0)

    // qv fragments (G B-operand): 5 q-tiles (rows qb..qb+79, clamped)
    v8s qvf0[5], qvf1[5];
#pragma unroll
    for (int qt2 = 0; qt2 < 5; ++qt2) {
        int r = qb + qt2 * 16 + l16;
        if (r > 2047) r = 2047;
        qvf0[qt2] = *(const v8s*)(QV + (size_t)r * DHD + quad * 8);
        qvf1[qt2] = *(const v8s*)(QV + (size_t)r * DHD + 32 + quad * 8);
    }
    const v8s bq0 = *(const v8s*)(QU + (size_t)q * DHD + quad * 8);
    const v8s bq1 = *(const v8s*)(QU + (size_t)q * DHD + 32 + quad * 8);

    float m_run = -1e30f, l_run = 0.f;
    v4f accv[4];
#pragma unroll
    for (int r = 0; r < 4; ++r) accv[r] = (v4f){0.f, 0.f, 0.f, 0.f};

    for (int tt = 0; tt < 16; ++tt) {
        const int k0 = tt * 128;
        int jb0B = k0 - qb - 65; if (jb0B < 0) jb0B = 0;
        const int jb0_1 = (tt <= t_mix) ? (1984 + k0 - qb) : jb0B;

        // issue pb-window loads early (fly under QK)
        v8s af0[3], af1[3];
        G_LOAD_AF(jb0_1)

        __syncthreads();   // stage(tt) complete & visible

        // QK^T from Kbuf (swizzled ds_read_b128); QU prescaled
        v4f sacc[8];
        __builtin_amdgcn_s_setprio(1);
#pragma unroll
        for (int nt = 0; nt < 8; ++nt) {
            int r = nt * 16 + l16;
            const unsigned short* kl = Kbuf + r * 64;
            v8s a0 = *(const v8s*)(kl + ((quad ^ (r & 7)) * 8));
            v8s a1 = *(const v8s*)(kl + (((4 + quad) ^ (r & 7)) * 8));
            v4f c = (v4f){0.f, 0.f, 0.f, 0.f};
            c = __builtin_amdgcn_mfma_f32_16x16x32_f16(a0, bq0, c, 0, 0, 0);
            c = __builtin_amdgcn_mfma_f32_16x16x32_f16(a1, bq1, c, 0, 0, 0);
            sacc[nt] = c;
        }
        __builtin_amdgcn_s_setprio(0);

        // G window 1 build + extraction (per tile class; block-uniform).
        // After the post-store barrier all QK reads of Kbuf are done ->
        // issue K(t+1) there; flight drains under extract+softmax+PV.
        if (tt < t_mix) {
            G_MFMA_STORE(4)
            __syncthreads();
            if (tt < 15) STAGE_K(tt + 1)
            EXTRACT_A(0)
        } else if (tt == t_mix) {
            G_MFMA_STORE(4)
            __syncthreads();
            if (tt < 15) STAGE_K(tt + 1)
            EXTRACT_A(1)
            __syncthreads();          // A reads done before B overwrites G
            G_LOAD_AF(jb0B)
            G_MFMA_STORE(5)
            __syncthreads();
            EXTRACT_B(2)
        } else {
            G_MFMA_STORE(5)
            __syncthreads();
            if (tt < 15) STAGE_K(tt + 1)
            if (tt == t_mix + 1) {
                EXTRACT_B(1)
            } else {
                EXTRACT_B(0)
            }
        }

        // online softmax with T13 defer-max: skip the accv rescale unless
        // some row's max grew by > 8 (P bounded by e^8 = 2981, fits fp16;
        // the common scale cancels in the final normalization).
        float tm = -1e30f;
#pragma unroll
        for (int nt = 0; nt < 8; ++nt)
#pragma unroll
            for (int reg = 0; reg < 4; ++reg) tm = fmaxf(tm, sacc[nt][reg]);
        tm = fmaxf(tm, __shfl_xor(tm, 16));
        tm = fmaxf(tm, __shfl_xor(tm, 32));
        if (__any(tm > m_run + 8.f)) {
            float mn = fmaxf(m_run, tm);
            float al = __expf(m_run - mn);
            float alr[4];
#pragma unroll
            for (int reg = 0; reg < 4; ++reg) alr[reg] = __shfl(al, quad * 4 + reg);
#pragma unroll
            for (int ntd = 0; ntd < 4; ++ntd)
#pragma unroll
                for (int reg = 0; reg < 4; ++reg) accv[ntd][reg] *= alr[reg];
            l_run *= al;
            m_run = mn;
        }
        float rs = 0.f;
#pragma unroll
        for (int nt = 0; nt < 8; ++nt)
#pragma unroll
            for (int reg = 0; reg < 4; ++reg) {
                sacc[nt][reg] = __expf(sacc[nt][reg] - m_run);
                rs += sacc[nt][reg];
            }
        rs += __shfl_xor(rs, 16);
        rs += __shfl_xor(rs, 32);
        l_run += rs;

        // pack P to fp16 word-pairs
        unsigned pk[8][2];
#pragma unroll
        for (int nt = 0; nt < 8; ++nt) {
            pk[nt][0] = pkh(sacc[nt][0], sacc[nt][1]);
            pk[nt][1] = pkh(sacc[nt][2], sacc[nt][3]);
        }

        // PV: A-fragment via shfl transpose, B from Vbuf (swizzled)
        const int sA = l16 + ((quad & 1) * 32);
        const bool hi = (quad >= 2);
#pragma unroll
        for (int c4 = 0; c4 < 4; ++c4) {
            unsigned a0A = __shfl((int)pk[c4 * 2][0], sA);
            unsigned a1A = __shfl((int)pk[c4 * 2][1], sA);
            unsigned a0B = __shfl((int)pk[c4 * 2][0], sA + 16);
            unsigned a1B = __shfl((int)pk[c4 * 2][1], sA + 16);
            unsigned b0A = __shfl((int)pk[c4 * 2 + 1][0], sA);
            unsigned b1A = __shfl((int)pk[c4 * 2 + 1][1], sA);
            unsigned b0B = __shfl((int)pk[c4 * 2 + 1][0], sA + 16);
            unsigned b1B = __shfl((int)pk[c4 * 2 + 1][1], sA + 16);
            union { unsigned u[4]; v8s v; } apu;
            apu.u[0] = hi ? b0A : a0A;
            apu.u[1] = hi ? b1A : a1A;
            apu.u[2] = hi ? b0B : a0B;
            apu.u[3] = hi ? b1B : a1B;
            __builtin_amdgcn_s_setprio(1);
#pragma unroll
            for (int ntd = 0; ntd < 4; ++ntd) {
                int d = ntd * 16 + l16;
                v8s bv8 = *(const v8s*)(Vbuf + d * 128 +
                                        (((c4 * 4 + quad) ^ (d & 15)) * 8));
                accv[ntd] = __builtin_amdgcn_mfma_f32_16x16x32_f16(apu.v, bv8, accv[ntd], 0, 0, 0);
            }
            __builtin_amdgcn_s_setprio(0);
        }

        __syncthreads();   // all waves done with Vbuf/Gb; K(t+1) already drained
        if (tt < 15) STAGE_V(tt + 1)
    }
#undef STAGE_K
#undef STAGE_V
#undef G_LOAD_AF
#undef G_MFMA_STORE
#undef EXTRACT_A
#undef EXTRACT_B

    // epilogue: each wave owns its 16 q-rows completely.
    const int bb = g >> 3, h = g & 7;
    float inv[4];
#pragma unroll
    for (int reg = 0; reg < 4; ++reg)
        inv[reg] = 1.f / __shfl(l_run, quad * 4 + reg);
#pragma unroll
    for (int ntd = 0; ntd < 4; ++ntd)
#pragma unroll
        for (int reg = 0; reg < 4; ++reg) {
            int qq = q0w + quad * 4 + reg;
            ctx[((size_t)(bb * S_LEN + qq)) * DM + h * DHD + ntd * 16 + l16] =
                f2h(accv[ntd][reg] * inv[reg]);
        }
}

// ---------------------------------------------------------------------------
// out_mfma: dbuf-staged + dense epilogue (r20, ~2us).
// ---------------------------------------------------------------------------
__global__ __launch_bounds__(256)
void out_mfma(const float* __restrict__ bo, const char* __restrict__ wsb,
              float* __restrict__ out)
{
    __shared__ __align__(16) unsigned char ORAW[65536];    // 64 KB (2x A+B)
    float* TO = (float*)ORAW;                              // epilogue [64][132]

    const int t = threadIdx.x;
    const int wave = t >> 6, lane = t & 63;
    const int quad = lane >> 4, l16 = lane & 15;
    const int wm = wave >> 1, wn = wave & 1;
    const unsigned short* matA = (const unsigned short*)(wsb + BY_WT)
                                 + (size_t)4 * WT_MAT_HALFS
                                 + (size_t)(blockIdx.y * 128) * 512;
    const unsigned short* matB = (const unsigned short*)(wsb + BY_CTX)
                                 + (size_t)(blockIdx.x * 128) * 512;

    const int rowl = lane >> 3, chl = lane & 7;

#define OSTAGE(KB, AB, BB)                                                    \
    {                                                                         \
        _Pragma("unroll")                                                     \
        for (int jj = 0; jj < 4; ++jj) {                                      \
            const int j = wave * 4 + jj;                                      \
            const int r = j * 8 + rowl;                                       \
            const int c = chl ^ (r & 7);                                      \
            __builtin_amdgcn_global_load_lds(                                 \
                (const __attribute__((address_space(1))) unsigned int*)       \
                    (matA + (size_t)r * 512 + (KB) * 64 + c * 8),             \
                (__attribute__((address_space(3))) unsigned int*)             \
                    ((AB) + j * 512), 16, 0, 0);                              \
            __builtin_amdgcn_global_load_lds(                                 \
                (const __attribute__((address_space(1))) unsigned int*)       \
                    (matB + (size_t)r * 512 + (KB) * 64 + c * 8),             \
                (__attribute__((address_space(3))) unsigned int*)             \
                    ((BB) + j * 512), 16, 0, 0);                              \
        }                                                                     \
    }

#define OCOMPUTE(AB, BB)                                                      \
    {                                                                         \
        v8s af0[4], af1[4], bf0[4], bf1[4];                                   \
        _Pragma("unroll")                                                     \
        for (int i = 0; i < 4; ++i) {                                         \
            int rA = wm * 64 + i * 16 + l16;                                  \
            const unsigned short* al = (AB) + rA * 64;                        \
            af0[i] = *(const v8s*)(al + ((quad ^ (rA & 7)) * 8));             \
            af1[i] = *(const v8s*)(al + (((4 + quad) ^ (rA & 7)) * 8));       \
            int rB = wn * 64 + i * 16 + l16;                                  \
            const unsigned short* bl = (BB) + rB * 64;                        \
            bf0[i] = *(const v8s*)(bl + ((quad ^ (rB & 7)) * 8));             \
            bf1[i] = *(const v8s*)(bl + (((4 + quad) ^ (rB & 7)) * 8));       \
        }                                                                     \
        _Pragma("unroll")                                                     \
        for (int i = 0; i < 4; ++i)                                           \
            _Pragma("unroll")                                                 \
            for (int j = 0; j < 4; ++j) {                                     \
                acc[i][j] = __builtin_amdgcn_mfma_f32_16x16x32_f16(af0[i], bf0[j], acc[i][j], 0, 0, 0); \
                acc[i][j] = __builtin_amdgcn_mfma_f32_16x16x32_f16(af1[i], bf1[j], acc[i][j], 0, 0, 0); \
            }                                                                 \
    }

    v4f acc[4][4];
#pragma unroll
    for (int i = 0; i < 4; ++i)
#pragma unroll
        for (int j = 0; j < 4; ++j) acc[i][j] = (v4f){0.f, 0.f, 0.f, 0.f};

    {
        unsigned short* A0 = (unsigned short*)ORAW;
        unsigned short* B0 = (unsigned short*)ORAW + 8192;
        unsigned short* A1 = (unsigned short*)ORAW + 16384;
        unsigned short* B1 = (unsigned short*)ORAW + 24576;
        OSTAGE(0, A0, B0)
#pragma unroll
        for (int kb = 0; kb < 8; ++kb) {
            __syncthreads();
            if (kb < 7) {
                if ((kb & 1) == 0) { OSTAGE(kb + 1, A1, B1) }
                else               { OSTAGE(kb + 1, A0, B0) }
            }
            if ((kb & 1) == 0) { OCOMPUTE(A0, B0) }
            else               { OCOMPUTE(A1, B1) }
        }
        __syncthreads();   // staging dead; TO alias safe
    }
#undef OSTAGE
#undef OCOMPUTE

    const int n0blk = blockIdx.y * 128;
    const int s0blk = blockIdx.x * 128;

    for (int hs = 0; hs < 2; ++hs) {
        if (wn == hs) {
#pragma unroll
            for (int i = 0; i < 4; ++i) {
                int n_loc = wm * 64 + i * 16 + quad * 4;
#pragma unroll
                for (int j = 0; j < 4; ++j) {
                    int s_loc = j * 16 + l16;
                    *(v4f*)&TO[s_loc * 132 + n_loc] = acc[i][j];
                }
            }
        }
        __syncthreads();
        {
            const int col4 = t & 31, rowb = t >> 5;
            float4 b4 = *(const float4*)(bo + n0blk + col4 * 4);
#pragma unroll
            for (int ii = 0; ii < 8; ++ii) {
                int row = rowb + ii * 8;
                int s = s0blk + hs * 64 + row;
                const float* tr = &TO[row * 132 + col4 * 4];
                float4 v = *(const float4*)tr;
                *(float4*)(out + (size_t)s * DM + n0blk + col4 * 4) =
                    make_float4(v.x + b4.x, v.y + b4.y, v.z + b4.z, v.w + b4.w);
            }
        }
        __syncthreads();
    }
}

// Fallback when ws_size is insufficient: clean mismatch instead of OOB writes.
__global__ void zero_fill(float* __restrict__ p, int n)
{
    int i = blockIdx.x * 256 + threadIdx.x;
    if (i < n) p[i] = 0.f;
}

// ---------------------------------------------------------------------------
extern "C" void kernel_launch(void* const* d_in, const int* in_sizes, int n_in,
                              void* d_out, int out_size, void* d_ws, size_t ws_size,
                              hipStream_t stream)
{
    const float* x   = (const float*)d_in[0];
    const float* pos = (const float*)d_in[1];
    const float* Wq  = (const float*)d_in[2];
    const float* bq  = (const float*)d_in[3];
    const float* Wk  = (const float*)d_in[4];
    const float* bk  = (const float*)d_in[5];
    const float* Wv  = (const float*)d_in[6];
    const float* bv  = (const float*)d_in[7];
    const float* Wp  = (const float*)d_in[8];
    const float* u   = (const float*)d_in[9];
    const float* v   = (const float*)d_in[10];
    const float* Wo  = (const float*)d_in[11];
    const float* bo  = (const float*)d_in[12];
    char* wsb  = (char*)d_ws;
    float* out = (float*)d_out;

    // Workspace guard (no Ppos tensor anymore).
    if (ws_size < (size_t)BY_END + 1024) {
        zero_fill<<<(out_size + 255) / 256, 256, 0, stream>>>(out, out_size);
        return;
    }

    // 1. dtype prep (inputs + weights, single dispatch)
    prep<<<dim3(4416), 256, 0, stream>>>(x, pos, Wq, Wk, Wv, Wp, Wo, wsb);

    // 2. projections (fp16 MFMA, 8-wave dbuf-staged; QU/QV prescaled)
    proj_mfma<<<dim3(32, 4, 4), 512, 0, stream>>>(bq, bk, bv, u, v, wsb);

    // 3. fused attention (single dispatch, all 16 batch-heads, XCD-swizzled)
    attn_fused<<<dim3(NBH * 32), 256, 0, stream>>>(
        (const unsigned short*)(wsb + BY_QU),
        (const unsigned short*)(wsb + BY_K),
        (const unsigned short*)(wsb + BY_VT),
        (const unsigned short*)(wsb + BY_QV),
        (const unsigned short*)(wsb + BY_PB),
        (unsigned short*)(wsb + BY_CTX));

    // 4. output projection (fp16 MFMA, dbuf-staged, dense epilogue, fp32 out)
    out_mfma<<<dim3(32, 4), 256, 0, stream>>>(bo, wsb, out);
}